// Round 11
// baseline (327.574 us; speedup 1.0000x reference)
//
#include <hip/hip_runtime.h>
#include <hip/hip_bf16.h>

// InfoNCE fused: loss = (1/N) sum_i [ log(sum_j exp(sim_ij)) - sim_ii ]
// sim = (z1/||z1||)@(z2/||z2||)^T / tau.  lse over the FULL row.
//
// z1f = bf16(z1n * log2(e)/tau) so exp(sim) = exp2(MFMA output).
// exp2 via Schraudolph bit-trick (R8: proved trans unit was NOT the wall).
//
// R18 vs R16/R17: two consecutive container failures with the cooperative
// kernel present (prior infra rate 1/9) -> hipLaunchCooperativeKernel under
// graph capture is the likely culprit (capture invalidated before the
// host-side fallback can engage). DROP coop entirely. Test the launch-gap
// theory capture-safely instead: fuse finalize into main via a completion
// counter -- each row-block vx has exactly CS=64 contributor blocks; the
// 64th (ticket via device-scope atomicAdd after __threadfence) re-reads
// the 256 rowsums coherently (atomicAdd(p,0.0f) = L2 RMW) and does the
// log2/subtract/reduce inline. 3 kernels -> 2, one gap removed.
// R1-R8 invariant: dur_us - sum(kernels) ~ 47-50us constant -> either
// ~16us/launch x3 or fixed harness cost. This round splits those:
// predict dur 106 -> ~88-92 if per-launch; unchanged if fixed.
// Main body = R8-verified 46us kernel, byte-identical inner loop.

typedef __bf16  bf16x8 __attribute__((ext_vector_type(8)));
typedef __bf16  bf16x4 __attribute__((ext_vector_type(4)));
typedef float   f32x4  __attribute__((ext_vector_type(4)));

#if __has_builtin(__builtin_amdgcn_logf)
#define LOG2F(x) __builtin_amdgcn_logf(x)    // raw v_log_f32
#else
#define LOG2F(x) log2f(x)
#endif

// Schraudolph fast exp2: 2^x ~= bitcast_f32((int)(x*2^23 + C)).
// C tuned mean-zero over uniform frac: (127<<23) - 0.05756*2^23.
// x in [-29.2, 29.2] -> no over/underflow. 3 full-rate VALU ops.
__device__ __forceinline__ float exp2_schraudolph(float x) {
    float y = fmaf(x, 8388608.0f, 1064870379.0f);
    return __int_as_float((int)y);
}

#define DDIM   64
#define TILEB  2048         // bytes per fragment-ordered 16-col tile
#define NSETS  4            // 16-row MFMA sets per wave (64 rows/wave)
#define NW     4            // waves per block
#define BM     (NW * NSETS * 16)   // 256 rows per block
#define CS     64           // column splits -> grid (64,64) = 4096 blocks
#define LDSB   32768        // colspan(256) * 128 B  (N == 16384)

#define GLOAD_LDS(g, l)                                                      \
    __builtin_amdgcn_global_load_lds(                                        \
        (const __attribute__((address_space(1))) void*)(g),                  \
        (__attribute__((address_space(3))) void*)(l), 16, 0, 0)

// ---------------------------------------------------------------- normalize
// One block per 16-row tile. Thread (r = tid>>4, c = tid&15) loads
// z[row, 4c..4c+4), reduces ||row|| over its 16-lane group, writes the 4
// bf16 values into fragment order:
//   byte off(tile) = (c>>3)*1024 + ((c>>1)&3)*256 + r*16 + (c&1)*8
// Same thread holds row i of both views -> posv[i] = dot(z1f_i, z2f_i).
// Zeroes rowsum, the per-row-block completion counters, and d_out.
__global__ __launch_bounds__(256) void norm_frag_kernel(
    const float* __restrict__ z1, const float* __restrict__ z2,
    __hip_bfloat16* __restrict__ z1f, __hip_bfloat16* __restrict__ z2f,
    float* __restrict__ rowsum, float* __restrict__ posv,
    int* __restrict__ cnt, float* __restrict__ out, float scale1, int N)
{
    const int tid  = threadIdx.x;
    const int r    = tid >> 4, c = tid & 15;
    const int tile = blockIdx.x;
    const size_t row = (size_t)tile * 16 + r;
    const size_t off = (size_t)tile * TILEB
                     + ((c >> 3) << 10) + (((c >> 1) & 3) << 8)
                     + (r << 4) + ((c & 1) << 3);

    bf16x4 o1, o2;
    {
        float4 v = *(const float4*)(z1 + row * DDIM + c * 4);
        float ss = v.x*v.x + v.y*v.y + v.z*v.z + v.w*v.w;
        #pragma unroll
        for (int o = 8; o; o >>= 1) ss += __shfl_xor(ss, o);
        float inv = scale1 / fmaxf(sqrtf(ss), 1e-12f);
        o1 = (bf16x4){ __float2bfloat16(v.x*inv), __float2bfloat16(v.y*inv),
                       __float2bfloat16(v.z*inv), __float2bfloat16(v.w*inv) };
        *(bf16x4*)((char*)z1f + off) = o1;
    }
    {
        float4 v = *(const float4*)(z2 + row * DDIM + c * 4);
        float ss = v.x*v.x + v.y*v.y + v.z*v.z + v.w*v.w;
        #pragma unroll
        for (int o = 8; o; o >>= 1) ss += __shfl_xor(ss, o);
        float inv = 1.0f / fmaxf(sqrtf(ss), 1e-12f);
        o2 = (bf16x4){ __float2bfloat16(v.x*inv), __float2bfloat16(v.y*inv),
                       __float2bfloat16(v.z*inv), __float2bfloat16(v.w*inv) };
        *(bf16x4*)((char*)z2f + off) = o2;
    }

    // posv[row] = dot of the bf16-rounded rows (log2-domain positive logit)
    float p = (float)o1[0]*(float)o2[0] + (float)o1[1]*(float)o2[1]
            + (float)o1[2]*(float)o2[2] + (float)o1[3]*(float)o2[3];
    #pragma unroll
    for (int o = 8; o; o >>= 1) p += __shfl_xor(p, o);
    if (c == 0) posv[row] = p;

    if (tid < 16) rowsum[(size_t)tile * 16 + tid] = 0.f;
    if (tile == 0) {
        if (tid < CS) cnt[tid] = 0;   // CS counters here; layout is [NBX] but NBX==CS
        if (tid == 0) *out = 0.f;
    }
}

// ---------------------------------------------------------------- main
// Per block: 256 rows (4 waves x 4 sets) x colspan=256 cols. Whole 32KB B
// panel staged to LDS up front, one barrier, 16 barrier-free iterations
// (R8 body). Then: rowsum atomics, threadfence, completion ticket; the
// LAST of the 64 blocks for this row-range computes finalize inline.
__global__ __launch_bounds__(256, 5) void infonce_main_kernel(
    const __hip_bfloat16* __restrict__ z1f,
    const __hip_bfloat16* __restrict__ z2f,
    float* __restrict__ rowsum, const float* __restrict__ posv,
    int* __restrict__ cnt, float* __restrict__ out, int N)
{
    __shared__ __align__(16) char ldsb[LDSB];   // 32 KB -> 5 blocks/CU
    __shared__ int isLast;

    const int tid  = threadIdx.x;
    const int wave = tid >> 6;
    const int lane = tid & 63;
    const int q    = lane >> 4;
    const int l15  = lane & 15;

    const int colspan = N / CS;          // 256
    const int ntiles  = colspan >> 4;    // 16
    const int c0      = blockIdx.y * colspan;
    const int vx      = blockIdx.x;
    const int wr      = vx * BM + wave * (NSETS * 16);

    const char* gB = (const char*)z2f + (size_t)(c0 >> 4) * TILEB;

    // stage the whole B panel: 32 chunks of 1KB, wave-interleaved
    for (int i = 0; i < 32 / NW; ++i) {
        const int c = i * NW + wave;
        GLOAD_LDS(gB + (c << 10) + lane * 16, ldsb + (c << 10));
    }

    // A fragments (fragment-ordered global, coalesced)
    bf16x8 a0[NSETS], a1[NSETS];
    #pragma unroll
    for (int s = 0; s < NSETS; ++s) {
        const char* ab = (const char*)z1f + (size_t)((wr >> 4) + s) * TILEB + lane * 16;
        a0[s] = *(const bf16x8*)(ab);
        a1[s] = *(const bf16x8*)(ab + 1024);
    }

    float sum[NSETS * 4];
    #pragma unroll
    for (int k = 0; k < NSETS * 4; ++k) sum[k] = 0.f;

    asm volatile("s_waitcnt vmcnt(0)" ::: "memory");
    __syncthreads();                      // LDS panel ready

    const char* bb = ldsb + lane * 16;
    const f32x4 kzero = {0.f, 0.f, 0.f, 0.f};

    #pragma unroll 4
    for (int t = 0; t < ntiles; ++t) {
        bf16x8 b0 = *(const bf16x8*)(bb + t * TILEB);
        bf16x8 b1 = *(const bf16x8*)(bb + t * TILEB + 1024);
        #pragma unroll
        for (int s = 0; s < NSETS; ++s) {
            f32x4 acc = __builtin_amdgcn_mfma_f32_16x16x32_bf16(a0[s], b0, kzero, 0, 0, 0);
            acc = __builtin_amdgcn_mfma_f32_16x16x32_bf16(a1[s], b1, acc, 0, 0, 0);
            sum[s * 4 + 0] += exp2_schraudolph(acc[0]);
            sum[s * 4 + 1] += exp2_schraudolph(acc[1]);
            sum[s * 4 + 2] += exp2_schraudolph(acc[2]);
            sum[s * 4 + 3] += exp2_schraudolph(acc[3]);
        }
    }

    // reduce each row-sum across the 16 lanes of the quad, then atomics
    #pragma unroll
    for (int k = 0; k < NSETS * 4; ++k) {
        float v = sum[k];
        #pragma unroll
        for (int o = 1; o < 16; o <<= 1) v += __shfl_xor(v, o);
        sum[k] = v;
    }
    if (l15 == 0) {
        #pragma unroll
        for (int s = 0; s < NSETS; ++s)
            #pragma unroll
            for (int i = 0; i < 4; ++i)
                atomicAdd(&rowsum[wr + s * 16 + q * 4 + i], sum[s * 4 + i]);
    }

    // ---------------- completion ticket; last block finalizes this vx ------
    __threadfence();                     // my rowsum atomics visible device-wide
    __syncthreads();                     // all waves of this block fenced
    if (tid == 0) {
        int v = atomicAdd(&cnt[vx], 1);
        isLast = (v == CS - 1);
    }
    __syncthreads();

    if (isLast) {
        // all 64 contributor blocks done; read coherently via L2 RMW
        const int row = vx * BM + tid;   // 256 threads == 256 rows
        float rs  = atomicAdd(&rowsum[row], 0.0f);
        float acc = (LOG2F(rs) - posv[row]) * (0.69314718055994531f / (float)N);
        #pragma unroll
        for (int o = 32; o; o >>= 1) acc += __shfl_xor(acc, o);
        if ((tid & 63) == 0) atomicAdd(out, acc);
    }
}

// ---------------------------------------------------------------- launch
extern "C" void kernel_launch(void* const* d_in, const int* in_sizes, int n_in,
                              void* d_out, int out_size, void* d_ws, size_t ws_size,
                              hipStream_t stream)
{
    const float* z1 = (const float*)d_in[0];
    const float* z2 = (const float*)d_in[1];
    const int N = in_sizes[0] / DDIM;   // 16384

    char* ws = (char*)d_ws;
    __hip_bfloat16* z1f = (__hip_bfloat16*)ws;                  // N*128 B (2 MB)
    __hip_bfloat16* z2f = z1f + (size_t)N * DDIM;               // N*128 B (2 MB)
    float* rowsum = (float*)(ws + 2 * (size_t)N * DDIM * 2);    // N*4 B
    float* posv   = rowsum + N;                                 // N*4 B
    int*   cnt    = (int*)(posv + N);                           // 64*4 B

    const float kScale = 28.853900817779268f;   // log2(e) / 0.05

    norm_frag_kernel<<<N / 16, 256, 0, stream>>>(z1, z2, z1f, z2f, rowsum,
                                                 posv, cnt, (float*)d_out,
                                                 kScale, N);

    dim3 grid(N / BM, CS);
    infonce_main_kernel<<<grid, NW * 64, 0, stream>>>(z1f, z2f, rowsum, posv,
                                                      cnt, (float*)d_out, N);
}

// Round 12
// 103.894 us; speedup vs baseline: 3.1530x; 3.1530x over previous
//
#include <hip/hip_runtime.h>
#include <hip/hip_bf16.h>

// InfoNCE fused: loss = (1/N) sum_i [ log(sum_j exp(sim_ij)) - sim_ii ]
// sim = (z1/||z1||)@(z2/||z2||)^T / tau.  lse over the FULL row.
//
// z1f = bf16(z1n * log2(e)/tau) so exp(sim) = exp2(MFMA output).
// exp2 via Schraudolph bit-trick (R8: proved trans unit was NOT the wall).
//
// R19 vs R18 (280us main, 6x regression): the per-block __threadfence()
// was the killer -- device-scope fence on gfx950 = L2 writeback+invalidate
// (cross-XCD visibility), 4096 of them destroyed the z1f/z2f L2 working
// set (HBM 94GB/s churn, MfmaUtil 5%). ALSO the extra __shared__ int
// pushed LDS to 33280 -> 4 blocks/CU instead of 5.
// The fence is unnecessary: rowsum atomicAdds already resolve at a
// device-coherent point (R8 passes with absmax 0 across 8 XCDs). The
// ticket only needs "my atomics COMPLETED before my ticket" = s_waitcnt
// vmcnt(0) (atomics are VMEM ops, vmcnt retires on completion). Last
// block reads via atomicAdd(p,0.0f) RMW at the same coherent point.
// isLast flag goes through ldsb[0] (dead after compute) -> LDS stays
// 32768 -> 5 blocks/CU. Main body = R8-verified 46us loop.
// Predict: main ~47-48us, norm ~5us, dur_us ~88-95 (one launch gap
// removed; R8->R11 delta showed ~10us/launch). absmax 0.

typedef __bf16  bf16x8 __attribute__((ext_vector_type(8)));
typedef __bf16  bf16x4 __attribute__((ext_vector_type(4)));
typedef float   f32x4  __attribute__((ext_vector_type(4)));

#if __has_builtin(__builtin_amdgcn_logf)
#define LOG2F(x) __builtin_amdgcn_logf(x)    // raw v_log_f32
#else
#define LOG2F(x) log2f(x)
#endif

// Schraudolph fast exp2: 2^x ~= bitcast_f32((int)(x*2^23 + C)).
// C tuned mean-zero over uniform frac: (127<<23) - 0.05756*2^23.
// x in [-29.2, 29.2] -> no over/underflow. 3 full-rate VALU ops.
__device__ __forceinline__ float exp2_schraudolph(float x) {
    float y = fmaf(x, 8388608.0f, 1064870379.0f);
    return __int_as_float((int)y);
}

#define DDIM   64
#define TILEB  2048         // bytes per fragment-ordered 16-col tile
#define NSETS  4            // 16-row MFMA sets per wave (64 rows/wave)
#define NW     4            // waves per block
#define BM     (NW * NSETS * 16)   // 256 rows per block
#define CS     64           // column splits -> grid (64,64) = 4096 blocks
#define LDSB   32768        // colspan(256) * 128 B  (N == 16384)

#define GLOAD_LDS(g, l)                                                      \
    __builtin_amdgcn_global_load_lds(                                        \
        (const __attribute__((address_space(1))) void*)(g),                  \
        (__attribute__((address_space(3))) void*)(l), 16, 0, 0)

// ---------------------------------------------------------------- normalize
// One block per 16-row tile. Thread (r = tid>>4, c = tid&15) loads
// z[row, 4c..4c+4), reduces ||row|| over its 16-lane group, writes the 4
// bf16 values into fragment order:
//   byte off(tile) = (c>>3)*1024 + ((c>>1)&3)*256 + r*16 + (c&1)*8
// Same thread holds row i of both views -> posv[i] = dot(z1f_i, z2f_i).
// Zeroes rowsum, the per-row-block completion counters, and d_out.
__global__ __launch_bounds__(256) void norm_frag_kernel(
    const float* __restrict__ z1, const float* __restrict__ z2,
    __hip_bfloat16* __restrict__ z1f, __hip_bfloat16* __restrict__ z2f,
    float* __restrict__ rowsum, float* __restrict__ posv,
    int* __restrict__ cnt, float* __restrict__ out, float scale1, int N)
{
    const int tid  = threadIdx.x;
    const int r    = tid >> 4, c = tid & 15;
    const int tile = blockIdx.x;
    const size_t row = (size_t)tile * 16 + r;
    const size_t off = (size_t)tile * TILEB
                     + ((c >> 3) << 10) + (((c >> 1) & 3) << 8)
                     + (r << 4) + ((c & 1) << 3);

    bf16x4 o1, o2;
    {
        float4 v = *(const float4*)(z1 + row * DDIM + c * 4);
        float ss = v.x*v.x + v.y*v.y + v.z*v.z + v.w*v.w;
        #pragma unroll
        for (int o = 8; o; o >>= 1) ss += __shfl_xor(ss, o);
        float inv = scale1 / fmaxf(sqrtf(ss), 1e-12f);
        o1 = (bf16x4){ __float2bfloat16(v.x*inv), __float2bfloat16(v.y*inv),
                       __float2bfloat16(v.z*inv), __float2bfloat16(v.w*inv) };
        *(bf16x4*)((char*)z1f + off) = o1;
    }
    {
        float4 v = *(const float4*)(z2 + row * DDIM + c * 4);
        float ss = v.x*v.x + v.y*v.y + v.z*v.z + v.w*v.w;
        #pragma unroll
        for (int o = 8; o; o >>= 1) ss += __shfl_xor(ss, o);
        float inv = 1.0f / fmaxf(sqrtf(ss), 1e-12f);
        o2 = (bf16x4){ __float2bfloat16(v.x*inv), __float2bfloat16(v.y*inv),
                       __float2bfloat16(v.z*inv), __float2bfloat16(v.w*inv) };
        *(bf16x4*)((char*)z2f + off) = o2;
    }

    // posv[row] = dot of the bf16-rounded rows (log2-domain positive logit)
    float p = (float)o1[0]*(float)o2[0] + (float)o1[1]*(float)o2[1]
            + (float)o1[2]*(float)o2[2] + (float)o1[3]*(float)o2[3];
    #pragma unroll
    for (int o = 8; o; o >>= 1) p += __shfl_xor(p, o);
    if (c == 0) posv[row] = p;

    if (tid < 16) rowsum[(size_t)tile * 16 + tid] = 0.f;
    if (tile == 0) {
        if (tid < CS) cnt[tid] = 0;   // one counter per row-block (NBX==CS==64)
        if (tid == 0) *out = 0.f;
    }
}

// ---------------------------------------------------------------- main
// Per block: 256 rows (4 waves x 4 sets) x colspan=256 cols. Whole 32KB B
// panel staged to LDS up front, one barrier, 16 barrier-free iterations
// (R8 body). Then: rowsum atomics, s_waitcnt vmcnt(0) (atomics completed
// at device-coherent point -- NO threadfence, no L2 flush), completion
// ticket; the LAST of the 64 contributor blocks finalizes its 256 rows
// inline, reading rowsum coherently via atomicAdd(p, 0.0f).
__global__ __launch_bounds__(256, 5) void infonce_main_kernel(
    const __hip_bfloat16* __restrict__ z1f,
    const __hip_bfloat16* __restrict__ z2f,
    float* __restrict__ rowsum, const float* __restrict__ posv,
    int* __restrict__ cnt, float* __restrict__ out, int N)
{
    __shared__ __align__(16) char ldsb[LDSB];   // 32 KB exactly -> 5 blocks/CU

    const int tid  = threadIdx.x;
    const int wave = tid >> 6;
    const int lane = tid & 63;
    const int q    = lane >> 4;
    const int l15  = lane & 15;

    const int colspan = N / CS;          // 256
    const int ntiles  = colspan >> 4;    // 16
    const int c0      = blockIdx.y * colspan;
    const int vx      = blockIdx.x;
    const int wr      = vx * BM + wave * (NSETS * 16);

    const char* gB = (const char*)z2f + (size_t)(c0 >> 4) * TILEB;

    // stage the whole B panel: 32 chunks of 1KB, wave-interleaved
    for (int i = 0; i < 32 / NW; ++i) {
        const int c = i * NW + wave;
        GLOAD_LDS(gB + (c << 10) + lane * 16, ldsb + (c << 10));
    }

    // A fragments (fragment-ordered global, coalesced)
    bf16x8 a0[NSETS], a1[NSETS];
    #pragma unroll
    for (int s = 0; s < NSETS; ++s) {
        const char* ab = (const char*)z1f + (size_t)((wr >> 4) + s) * TILEB + lane * 16;
        a0[s] = *(const bf16x8*)(ab);
        a1[s] = *(const bf16x8*)(ab + 1024);
    }

    float sum[NSETS * 4];
    #pragma unroll
    for (int k = 0; k < NSETS * 4; ++k) sum[k] = 0.f;

    asm volatile("s_waitcnt vmcnt(0)" ::: "memory");
    __syncthreads();                      // LDS panel ready

    const char* bb = ldsb + lane * 16;
    const f32x4 kzero = {0.f, 0.f, 0.f, 0.f};

    #pragma unroll 4
    for (int t = 0; t < ntiles; ++t) {
        bf16x8 b0 = *(const bf16x8*)(bb + t * TILEB);
        bf16x8 b1 = *(const bf16x8*)(bb + t * TILEB + 1024);
        #pragma unroll
        for (int s = 0; s < NSETS; ++s) {
            f32x4 acc = __builtin_amdgcn_mfma_f32_16x16x32_bf16(a0[s], b0, kzero, 0, 0, 0);
            acc = __builtin_amdgcn_mfma_f32_16x16x32_bf16(a1[s], b1, acc, 0, 0, 0);
            sum[s * 4 + 0] += exp2_schraudolph(acc[0]);
            sum[s * 4 + 1] += exp2_schraudolph(acc[1]);
            sum[s * 4 + 2] += exp2_schraudolph(acc[2]);
            sum[s * 4 + 3] += exp2_schraudolph(acc[3]);
        }
    }

    // reduce each row-sum across the 16 lanes of the quad, then atomics
    #pragma unroll
    for (int k = 0; k < NSETS * 4; ++k) {
        float v = sum[k];
        #pragma unroll
        for (int o = 1; o < 16; o <<= 1) v += __shfl_xor(v, o);
        sum[k] = v;
    }
    if (l15 == 0) {
        #pragma unroll
        for (int s = 0; s < NSETS; ++s)
            #pragma unroll
            for (int i = 0; i < 4; ++i)
                atomicAdd(&rowsum[wr + s * 16 + q * 4 + i], sum[s * 4 + i]);
    }

    // ---- completion ticket (NO fence: atomics complete at coherent point)
    asm volatile("s_waitcnt vmcnt(0)" ::: "memory");  // my atomics retired
    __syncthreads();              // all waves retired; ldsb reads all done
    if (tid == 0) {
        int v = atomicAdd(&cnt[vx], 1);
        *(int*)ldsb = (v == CS - 1);      // reuse dead LDS for the flag
    }
    __syncthreads();

    if (*(const int*)ldsb) {
        // all 64 contributor blocks done; read coherently via L2 RMW
        const int row = vx * BM + tid;    // 256 threads == 256 rows
        float rs  = atomicAdd(&rowsum[row], 0.0f);
        float acc = (LOG2F(rs) - posv[row]) * (0.69314718055994531f / (float)N);
        #pragma unroll
        for (int o = 32; o; o >>= 1) acc += __shfl_xor(acc, o);
        if ((tid & 63) == 0) atomicAdd(out, acc);
    }
}

// ---------------------------------------------------------------- launch
extern "C" void kernel_launch(void* const* d_in, const int* in_sizes, int n_in,
                              void* d_out, int out_size, void* d_ws, size_t ws_size,
                              hipStream_t stream)
{
    const float* z1 = (const float*)d_in[0];
    const float* z2 = (const float*)d_in[1];
    const int N = in_sizes[0] / DDIM;   // 16384

    char* ws = (char*)d_ws;
    __hip_bfloat16* z1f = (__hip_bfloat16*)ws;                  // N*128 B (2 MB)
    __hip_bfloat16* z2f = z1f + (size_t)N * DDIM;               // N*128 B (2 MB)
    float* rowsum = (float*)(ws + 2 * (size_t)N * DDIM * 2);    // N*4 B
    float* posv   = rowsum + N;                                 // N*4 B
    int*   cnt    = (int*)(posv + N);                           // 64*4 B

    const float kScale = 28.853900817779268f;   // log2(e) / 0.05

    norm_frag_kernel<<<N / 16, 256, 0, stream>>>(z1, z2, z1f, z2f, rowsum,
                                                 posv, cnt, (float*)d_out,
                                                 kScale, N);

    dim3 grid(N / BM, CS);
    infonce_main_kernel<<<grid, NW * 64, 0, stream>>>(z1f, z2f, rowsum, posv,
                                                      cnt, (float*)d_out, N);
}